// Round 1
// baseline (214.044 us; speedup 1.0000x reference)
//
#include <hip/hip_runtime.h>

#define T_DIM 2048
#define C_DIM 64
#define TARGET 96

__global__ __launch_bounds__(256) void timesnet_pool_kernel(
    const float* __restrict__ feats,
    const float* __restrict__ mask,
    const int* __restrict__ valid_lengths,
    float* __restrict__ out,
    int BN)
{
    __shared__ float ldsF[T_DIM];
    __shared__ float ldsM[T_DIM];

    const int bc = blockIdx.x;           // b * C + c
    const int b  = bc / C_DIM;
    const int tid = threadIdx.x;

    // lengths = clip(valid_lengths, 1, T)
    int len = valid_lengths[b];
    if (len < 1) len = 1;
    if (len > T_DIM) len = T_DIM;
    const int offset = T_DIM - len;

    // Stage trailing window [offset, T) into LDS, aligned down to float4.
    const int astart = offset & ~3;            // 16B-aligned float index
    const int v0 = astart >> 2;                // first float4 index
    const int nv = (T_DIM >> 2) - v0;          // number of float4s to load

    const float4* __restrict__ fsrc = (const float4*)(feats + (size_t)bc * T_DIM);
    const float4* __restrict__ msrc = (const float4*)(mask  + (size_t)bc * T_DIM);
    float4* ldsF4 = (float4*)ldsF;
    float4* ldsM4 = (float4*)ldsM;

    for (int i = tid; i < nv; i += 256) {
        const int vi = v0 + i;
        ldsF4[vi] = fsrc[vi];
        ldsM4[vi] = msrc[vi];
    }
    __syncthreads();

    // Threads 0..95 -> features, 96..191 -> mask. Each computes one window avg.
    if (tid < 2 * TARGET) {
        const int arr = (tid >= TARGET) ? 1 : 0;
        const int j   = arr ? (tid - TARGET) : tid;

        int s = (len * j) / TARGET + offset;
        int e = (len * (j + 1) + TARGET - 1) / TARGET + offset;
        if (e > T_DIM) e = T_DIM;
        int cnt = e - s;
        if (cnt < 1) cnt = 1;

        const float* __restrict__ src = arr ? ldsM : ldsF;
        float sum = 0.0f;
        for (int t = s; t < e; ++t) sum += src[t];
        const float val = sum / (float)cnt;

        const size_t half = (size_t)BN * C_DIM * TARGET;
        out[(size_t)arr * half + (size_t)bc * TARGET + j] = val;
    }
}

extern "C" void kernel_launch(void* const* d_in, const int* in_sizes, int n_in,
                              void* d_out, int out_size, void* d_ws, size_t ws_size,
                              hipStream_t stream) {
    const float* feats = (const float*)d_in[0];
    const float* mask  = (const float*)d_in[1];
    const int*   vlen  = (const int*)d_in[2];
    // d_in[3] is target_len (=96), hardcoded as TARGET.
    float* out = (float*)d_out;

    const int BN = in_sizes[2];              // 2048
    const int grid = BN * C_DIM;             // one block per (b, c) row

    timesnet_pool_kernel<<<grid, 256, 0, stream>>>(feats, mask, vlen, out, BN);
}

// Round 3
// 203.248 us; speedup vs baseline: 1.0531x; 1.0531x over previous
//
#include <hip/hip_runtime.h>

#define T_DIM 2048
#define C_DIM 64
#define TARGET 96

typedef float floatx4 __attribute__((ext_vector_type(4)));

__global__ __launch_bounds__(256) void timesnet_pool_kernel(
    const float* __restrict__ feats,
    const float* __restrict__ mask,
    const int* __restrict__ valid_lengths,
    float* __restrict__ out,
    int BN)
{
    __shared__ float ldsF[T_DIM];
    __shared__ float ldsM[T_DIM];

    const int bc = blockIdx.x;           // b * C + c
    const int b  = bc / C_DIM;
    const int tid = threadIdx.x;

    // lengths = clip(valid_lengths, 1, T)
    int len = valid_lengths[b];
    if (len < 1) len = 1;
    if (len > T_DIM) len = T_DIM;
    const int offset = T_DIM - len;

    // Stage trailing window [offset, T) into LDS, aligned down to float4.
    const int astart = offset & ~3;            // 16B-aligned float index
    const int v0 = astart >> 2;                // first float4 index
    const int nv = (T_DIM >> 2) - v0;          // number of float4s to load

    const floatx4* __restrict__ fsrc = (const floatx4*)(feats + (size_t)bc * T_DIM);
    const floatx4* __restrict__ msrc = (const floatx4*)(mask  + (size_t)bc * T_DIM);
    floatx4* ldsF4 = (floatx4*)ldsF;
    floatx4* ldsM4 = (floatx4*)ldsM;

    for (int i = tid; i < nv; i += 256) {
        const int vi = v0 + i;
        // Nontemporal: pure streaming input, no reuse — don't pollute L2/L3.
        ldsF4[vi] = __builtin_nontemporal_load(&fsrc[vi]);
        ldsM4[vi] = __builtin_nontemporal_load(&msrc[vi]);
    }
    __syncthreads();

    // Threads 0..95 -> features, 96..191 -> mask. Each computes one window avg.
    if (tid < 2 * TARGET) {
        const int arr = (tid >= TARGET) ? 1 : 0;
        const int j   = arr ? (tid - TARGET) : tid;

        int s = (len * j) / TARGET + offset;
        int e = (len * (j + 1) + TARGET - 1) / TARGET + offset;
        if (e > T_DIM) e = T_DIM;
        int cnt = e - s;
        if (cnt < 1) cnt = 1;

        const float* __restrict__ src = arr ? ldsM : ldsF;
        float sum = 0.0f;
        for (int t = s; t < e; ++t) sum += src[t];
        const float val = sum * __frcp_rn((float)cnt);

        const size_t half = (size_t)BN * C_DIM * TARGET;
        __builtin_nontemporal_store(val, &out[(size_t)arr * half + (size_t)bc * TARGET + j]);
    }
}

extern "C" void kernel_launch(void* const* d_in, const int* in_sizes, int n_in,
                              void* d_out, int out_size, void* d_ws, size_t ws_size,
                              hipStream_t stream) {
    const float* feats = (const float*)d_in[0];
    const float* mask  = (const float*)d_in[1];
    const int*   vlen  = (const int*)d_in[2];
    // d_in[3] is target_len (=96), hardcoded as TARGET.
    float* out = (float*)d_out;

    const int BN = in_sizes[2];              // 2048
    const int grid = BN * C_DIM;             // one block per (b, c) row

    timesnet_pool_kernel<<<grid, 256, 0, stream>>>(feats, mask, vlen, out, BN);
}